// Round 4
// baseline (534.103 us; speedup 1.0000x reference)
//
#include <hip/hip_runtime.h>

// B=4, C=256, CR=64, H=W=64, K=7, KK=49, GROUPS=16, GC=16
#define BN_EPS 1e-5f

typedef __bf16 bf16_t;
typedef __bf16 bf16x8 __attribute__((ext_vector_type(8)));
typedef __bf16 bf16x4 __attribute__((ext_vector_type(4)));
typedef __bf16 bf16x2 __attribute__((ext_vector_type(2)));
typedef float  floatx4 __attribute__((ext_vector_type(4)));

#define MFMA16(a, b, c) __builtin_amdgcn_mfma_f32_16x16x32_bf16((a), (b), (c), 0, 0, 0)

// ws layout: only xT (16384 px x 64 ch bf16 = 2 MB)
#define XT_OFF 0

// ---------------------------------------------------------------------------
// K1 conv1: one block per (b,h), 512 threads (2 waves/SIMD). w1 A-frags direct
// from global (L2-hot) with BN fold in regs; guide transpose staged in LDS.
// MFMA x[64o][64p]; +bias, ReLU; store xT[bp][o] (c-contiguous).
// ---------------------------------------------------------------------------
#define GTP 264

__global__ __launch_bounds__(512) void conv1_k(
    const float* __restrict__ guide, const float* __restrict__ w1,
    const float* __restrict__ gamma, const float* __restrict__ beta,
    const float* __restrict__ mean,  const float* __restrict__ var,
    bf16_t* __restrict__ xT)
{
    __shared__ __attribute__((aligned(16))) bf16_t gTs[64 * GTP];  // 33.8 KB
    const int b = blockIdx.x >> 6, h = blockIdx.x & 63;
    const int t = threadIdx.x;

    // stage guide row transposed: coalesced dword reads (lanes = p)
    const float* gsrc = guide + (size_t)b * 256 * 4096 + h * 64;
#pragma unroll
    for (int i = 0; i < 16; ++i) {
        const int idx = i * 512 + t;       // 8192 units = 128 c2 x 64 p
        const int c2 = idx >> 6, p = idx & 63;
        const float g0 = gsrc[(size_t)(2 * c2) * 4096 + p];
        const float g1 = gsrc[(size_t)(2 * c2 + 1) * 4096 + p];
        bf16x2 pk; pk[0] = (bf16_t)g0; pk[1] = (bf16_t)g1;
        *(bf16x2*)&gTs[p * GTP + 2 * c2] = pk;
    }
    __syncthreads();

    const int wv = t >> 6, ln = t & 63, l15 = ln & 15, q = ln >> 4;
    const int ot = wv & 3;          // o-tile: channels ot*16 .. +16
    const int ph = wv >> 2;         // p-half: pixels ph*32 .. +32
    const int o = ot * 16 + l15;    // A-row this lane reads
    const float iv = gamma[o] * rsqrtf(var[o] + BN_EPS);

    floatx4 acc[2] = {};
#pragma unroll
    for (int ks = 0; ks < 8; ++ks) {
        const float* wp = w1 + o * 256 + ks * 32 + q * 8;
        const float4 a0 = *(const float4*)(wp);
        const float4 a1 = *(const float4*)(wp + 4);
        bf16x8 a;
        a[0] = (bf16_t)(a0.x * iv); a[1] = (bf16_t)(a0.y * iv);
        a[2] = (bf16_t)(a0.z * iv); a[3] = (bf16_t)(a0.w * iv);
        a[4] = (bf16_t)(a1.x * iv); a[5] = (bf16_t)(a1.y * iv);
        a[6] = (bf16_t)(a1.z * iv); a[7] = (bf16_t)(a1.w * iv);
#pragma unroll
        for (int nt = 0; nt < 2; ++nt) {
            const bf16x8 bb = *(const bf16x8*)&gTs[(ph * 32 + nt * 16 + l15) * GTP + ks * 32 + q * 8];
            acc[nt] = MFMA16(a, bb, acc[nt]);
        }
    }
    float bi[4];
#pragma unroll
    for (int j = 0; j < 4; ++j) {
        const int o2 = ot * 16 + q * 4 + j;
        const float iv2 = gamma[o2] * rsqrtf(var[o2] + BN_EPS);
        bi[j] = beta[o2] - mean[o2] * iv2;
    }
#pragma unroll
    for (int nt = 0; nt < 2; ++nt) {
        const int p = ph * 32 + nt * 16 + l15;
        bf16x4 v;
#pragma unroll
        for (int j = 0; j < 4; ++j) v[j] = (bf16_t)fmaxf(acc[nt][j] + bi[j], 0.f);
        *(bf16x4*)(xT + ((size_t)(b * 64 + h) * 64 + p) * 64 + ot * 16 + q * 4) = v;
    }
}

// ---------------------------------------------------------------------------
// K2 conv2+agg fused, NO feature LDS: block = (g, b, h-pair), grid 2048.
// FETCH_SIZE==input-size across all prior variants proved feat re-reads are
// L2/L3-absorbed, so LDS-staging them only cost latency under the barrier and
// capped occupancy. Now:
//   phase1: MFMA wg[49k x 128px] = w2[g].xT (+b2) -> wgs bf16 (13.3 KB = ALL
//           the LDS); short barrier.
//   phase2: agg reads feature windows DIRECT from global as 3 predicated
//           aligned float4 quads per (di,ch) (cols w0-4..w0+7 cover taps
//           w0-3..w0+6); predicates exactly reproduce zero-padding; residual
//           captured from the di==3 center quad. 44 independent loads/thread.
// launch_bounds(256,6) -> 6 blocks/CU = 24 waves/CU; whole grid ~1.3
// residency generations. XCD = g%8 -> per-XCD feat slice ~2.1 MB L2-resident.
// ---------------------------------------------------------------------------
#define WGP 136    // wgs row pitch (bf16)

__global__ __launch_bounds__(256, 6) void fused_k(
    const bf16_t* __restrict__ xT, const float* __restrict__ w2,
    const float* __restrict__ b2,  const float* __restrict__ feat,
    float* __restrict__ out)
{
    __shared__ __attribute__((aligned(16))) bf16_t wgs[49 * WGP];  // 13.3 KB

    const int g = blockIdx.x & 15;
    const int rest = blockIdx.x >> 4;      // 0..127
    const int b = rest >> 5, hp = rest & 31;
    const int h0 = hp * 2;
    const int t = threadIdx.x;
    const int wv = t >> 6, ln = t & 63, l15 = ln & 15, q = ln >> 4;

    // ---- phase1 MFMA: wg[49 x 128] = w2[g] . xT ; A cvt'd from fp32 in regs ----
    {
        floatx4 acc[4][2] = {};
        const bf16_t* brow = xT + ((size_t)(b * 64 + h0) * 64 + wv * 32) * 64;
#pragma unroll
        for (int ks = 0; ks < 2; ++ks) {
            bf16x8 bfr[2];
            bfr[0] = *(const bf16x8*)(brow + l15 * 64 + ks * 32 + q * 8);
            bfr[1] = *(const bf16x8*)(brow + (16 + l15) * 64 + ks * 32 + q * 8);
#pragma unroll
            for (int mt = 0; mt < 4; ++mt) {
                int row = mt * 16 + l15; if (row > 48) row = 48;  // pad rows never stored
                const float* wp = w2 + (size_t)(g * 49 + row) * 64 + ks * 32 + q * 8;
                const float4 a0 = *(const float4*)(wp);
                const float4 a1 = *(const float4*)(wp + 4);
                bf16x8 a;
                a[0] = (bf16_t)a0.x; a[1] = (bf16_t)a0.y; a[2] = (bf16_t)a0.z; a[3] = (bf16_t)a0.w;
                a[4] = (bf16_t)a1.x; a[5] = (bf16_t)a1.y; a[6] = (bf16_t)a1.z; a[7] = (bf16_t)a1.w;
                acc[mt][0] = MFMA16(a, bfr[0], acc[mt][0]);
                acc[mt][1] = MFMA16(a, bfr[1], acc[mt][1]);
            }
        }
#pragma unroll
        for (int mt = 0; mt < 4; ++mt) {
#pragma unroll
            for (int j = 0; j < 4; ++j) {
                const int k = mt * 16 + q * 4 + j;
                if (k < 49) {
                    const float bias = b2[g * 49 + k];
                    wgs[k * WGP + wv * 32 + l15]      = (bf16_t)(acc[mt][0][j] + bias);
                    wgs[k * WGP + wv * 32 + 16 + l15] = (bf16_t)(acc[mt][1][j] + bias);
                }
            }
        }
    }
    __syncthreads();

    // ---- phase2 agg: thread = (wq, r, cp) -> 2 ch x 4 w, direct-global feat ----
    const int wq = t & 15, r = (t >> 4) & 1, cp = t >> 5;   // cp in [0,8)
    const int w0 = wq * 4;
    const int ch0 = cp * 2;
    const bool q0v = (w0 > 0);      // quad at w0-4 valid
    const bool q2v = (w0 < 60);     // quad at w0+4 valid

    float acc[2][4] = {};
    float resv[2][4];
    const float* fbase = feat + ((size_t)(b * 256 + g * 16 + ch0) * 64) * 64;

#pragma unroll
    for (int di = 0; di < 7; ++di) {
        const int hh = h0 + r + di - 3;
        const bool rv = (hh >= 0) && (hh < 64);

        bf16x4 warr[7];
        const bf16_t* wrow = &wgs[(di * 7) * WGP + r * 64 + w0];
#pragma unroll
        for (int dj = 0; dj < 7; ++dj) warr[dj] = *(const bf16x4*)(wrow + dj * WGP);

#pragma unroll
        for (int c = 0; c < 2; ++c) {
            const float* fb = fbase + (size_t)c * 4096 + hh * 64;
            floatx4 f0 = {0.f, 0.f, 0.f, 0.f};
            floatx4 f1 = {0.f, 0.f, 0.f, 0.f};
            floatx4 f2 = {0.f, 0.f, 0.f, 0.f};
            if (rv && q0v) f0 = *(const floatx4*)(fb + w0 - 4);
            if (rv)        f1 = *(const floatx4*)(fb + w0);
            if (rv && q2v) f2 = *(const floatx4*)(fb + w0 + 4);
            float fw[12];
#pragma unroll
            for (int j = 0; j < 4; ++j) {
                fw[j] = f0[j]; fw[4 + j] = f1[j]; fw[8 + j] = f2[j];
            }
            if (di == 3) {
#pragma unroll
                for (int x = 0; x < 4; ++x) resv[c][x] = f1[x];
            }
#pragma unroll
            for (int dj = 0; dj < 7; ++dj) {
                const bf16x4 wb = warr[dj];
#pragma unroll
                for (int x = 0; x < 4; ++x)
                    acc[c][x] = fmaf((float)wb[x], fw[x + dj + 1], acc[c][x]);
            }
        }
    }

    // residual (captured from di==3 center quad) + store
#pragma unroll
    for (int c = 0; c < 2; ++c) {
        const size_t ob = ((size_t)(b * 256 + g * 16 + ch0 + c) * 64 + h0 + r) * 64 + w0;
        float4 o;
        o.x = acc[c][0] + resv[c][0]; o.y = acc[c][1] + resv[c][1];
        o.z = acc[c][2] + resv[c][2]; o.w = acc[c][3] + resv[c][3];
        *(float4*)(out + ob) = o;
    }
}

extern "C" void kernel_launch(void* const* d_in, const int* in_sizes, int n_in,
                              void* d_out, int out_size, void* d_ws, size_t ws_size,
                              hipStream_t stream) {
    const float* feature = (const float*)d_in[0];
    const float* guide   = (const float*)d_in[1];
    const float* w1      = (const float*)d_in[2];
    const float* gamma   = (const float*)d_in[3];
    const float* beta    = (const float*)d_in[4];
    const float* mean    = (const float*)d_in[5];
    const float* var     = (const float*)d_in[6];
    const float* w2      = (const float*)d_in[7];
    const float* b2      = (const float*)d_in[8];
    float* out = (float*)d_out;

    bf16_t* xT = (bf16_t*)((char*)d_ws + XT_OFF);

    conv1_k<<<256, 512, 0, stream>>>(guide, w1, gamma, beta, mean, var, xT);
    fused_k<<<2048, 256, 0, stream>>>(xT, w2, b2, feature, out);
}

// Round 5
// 142.863 us; speedup vs baseline: 3.7386x; 3.7386x over previous
//
#include <hip/hip_runtime.h>

// B=4, C=256, CR=64, H=W=64, K=7, KK=49, GROUPS=16, GC=16
#define BN_EPS 1e-5f

typedef __bf16 bf16_t;
typedef __bf16 bf16x8 __attribute__((ext_vector_type(8)));
typedef __bf16 bf16x4 __attribute__((ext_vector_type(4)));
typedef __bf16 bf16x2 __attribute__((ext_vector_type(2)));
typedef float  floatx4 __attribute__((ext_vector_type(4)));

#define MFMA16(a, b, c) __builtin_amdgcn_mfma_f32_16x16x32_bf16((a), (b), (c), 0, 0, 0)

// ws layout: only xT (16384 px x 64 ch bf16 = 2 MB)
#define XT_OFF 0

// ---------------------------------------------------------------------------
// K1 conv1: one block per (b,h), 512 threads (2 waves/SIMD). w1 A-frags direct
// from global (L2-hot) with BN fold in regs; guide transpose staged in LDS.
// MFMA x[64o][64p]; +bias, ReLU; store xT[bp][o] (c-contiguous).
// ---------------------------------------------------------------------------
#define GTP 264

__global__ __launch_bounds__(512) void conv1_k(
    const float* __restrict__ guide, const float* __restrict__ w1,
    const float* __restrict__ gamma, const float* __restrict__ beta,
    const float* __restrict__ mean,  const float* __restrict__ var,
    bf16_t* __restrict__ xT)
{
    __shared__ __attribute__((aligned(16))) bf16_t gTs[64 * GTP];  // 33.8 KB
    const int b = blockIdx.x >> 6, h = blockIdx.x & 63;
    const int t = threadIdx.x;

    // stage guide row transposed: coalesced dword reads (lanes = p)
    const float* gsrc = guide + (size_t)b * 256 * 4096 + h * 64;
#pragma unroll
    for (int i = 0; i < 16; ++i) {
        const int idx = i * 512 + t;       // 8192 units = 128 c2 x 64 p
        const int c2 = idx >> 6, p = idx & 63;
        const float g0 = gsrc[(size_t)(2 * c2) * 4096 + p];
        const float g1 = gsrc[(size_t)(2 * c2 + 1) * 4096 + p];
        bf16x2 pk; pk[0] = (bf16_t)g0; pk[1] = (bf16_t)g1;
        *(bf16x2*)&gTs[p * GTP + 2 * c2] = pk;
    }
    __syncthreads();

    const int wv = t >> 6, ln = t & 63, l15 = ln & 15, q = ln >> 4;
    const int ot = wv & 3;          // o-tile: channels ot*16 .. +16
    const int ph = wv >> 2;         // p-half: pixels ph*32 .. +32
    const int o = ot * 16 + l15;    // A-row this lane reads
    const float iv = gamma[o] * rsqrtf(var[o] + BN_EPS);

    floatx4 acc[2] = {};
#pragma unroll
    for (int ks = 0; ks < 8; ++ks) {
        const float* wp = w1 + o * 256 + ks * 32 + q * 8;
        const float4 a0 = *(const float4*)(wp);
        const float4 a1 = *(const float4*)(wp + 4);
        bf16x8 a;
        a[0] = (bf16_t)(a0.x * iv); a[1] = (bf16_t)(a0.y * iv);
        a[2] = (bf16_t)(a0.z * iv); a[3] = (bf16_t)(a0.w * iv);
        a[4] = (bf16_t)(a1.x * iv); a[5] = (bf16_t)(a1.y * iv);
        a[6] = (bf16_t)(a1.z * iv); a[7] = (bf16_t)(a1.w * iv);
#pragma unroll
        for (int nt = 0; nt < 2; ++nt) {
            const bf16x8 bb = *(const bf16x8*)&gTs[(ph * 32 + nt * 16 + l15) * GTP + ks * 32 + q * 8];
            acc[nt] = MFMA16(a, bb, acc[nt]);
        }
    }
    float bi[4];
#pragma unroll
    for (int j = 0; j < 4; ++j) {
        const int o2 = ot * 16 + q * 4 + j;
        const float iv2 = gamma[o2] * rsqrtf(var[o2] + BN_EPS);
        bi[j] = beta[o2] - mean[o2] * iv2;
    }
#pragma unroll
    for (int nt = 0; nt < 2; ++nt) {
        const int p = ph * 32 + nt * 16 + l15;
        bf16x4 v;
#pragma unroll
        for (int j = 0; j < 4; ++j) v[j] = (bf16_t)fmaxf(acc[nt][j] + bi[j], 0.f);
        *(bf16x4*)(xT + ((size_t)(b * 64 + h) * 64 + p) * 64 + ot * 16 + q * 4) = v;
    }
}

// ---------------------------------------------------------------------------
// K2 conv2+agg fused, NO feature LDS: block = (g, b, h-pair), grid 2048.
//   phase1: MFMA wg[49k x 128px] = w2[g].xT (+b2) -> wgs bf16 (13.3 KB = ALL
//           the LDS); short barrier.
//   phase2: agg reads feature windows DIRECT from global as 3 predicated
//           aligned float4 quads per (di,ch); predicates reproduce the
//           zero-padding; residual re-loaded at the end from the always-valid
//           center quad (L1-hit). 42 independent loads/thread -> needs high
//           occupancy: NO min-waves launch bound (R4's (256,6) capped VGPRs
//           at 40 and spilled ~1.5 GB of scratch -> 450 us).
// XCD = g%8 -> per-XCD feat slice ~2.1 MB, L2-resident.
// ---------------------------------------------------------------------------
#define WGP 136    // wgs row pitch (bf16)

__global__ __launch_bounds__(256) void fused_k(
    const bf16_t* __restrict__ xT, const float* __restrict__ w2,
    const float* __restrict__ b2,  const float* __restrict__ feat,
    float* __restrict__ out)
{
    __shared__ __attribute__((aligned(16))) bf16_t wgs[49 * WGP];  // 13.3 KB

    const int g = blockIdx.x & 15;
    const int rest = blockIdx.x >> 4;      // 0..127
    const int b = rest >> 5, hp = rest & 31;
    const int h0 = hp * 2;
    const int t = threadIdx.x;
    const int wv = t >> 6, ln = t & 63, l15 = ln & 15, q = ln >> 4;

    // ---- phase1 MFMA: wg[49 x 128] = w2[g] . xT ; A cvt'd from fp32 in regs ----
    {
        floatx4 acc[4][2] = {};
        const bf16_t* brow = xT + ((size_t)(b * 64 + h0) * 64 + wv * 32) * 64;
#pragma unroll
        for (int ks = 0; ks < 2; ++ks) {
            bf16x8 bfr[2];
            bfr[0] = *(const bf16x8*)(brow + l15 * 64 + ks * 32 + q * 8);
            bfr[1] = *(const bf16x8*)(brow + (16 + l15) * 64 + ks * 32 + q * 8);
#pragma unroll
            for (int mt = 0; mt < 4; ++mt) {
                int row = mt * 16 + l15; if (row > 48) row = 48;  // pad rows never stored
                const float* wp = w2 + (size_t)(g * 49 + row) * 64 + ks * 32 + q * 8;
                const float4 a0 = *(const float4*)(wp);
                const float4 a1 = *(const float4*)(wp + 4);
                bf16x8 a;
                a[0] = (bf16_t)a0.x; a[1] = (bf16_t)a0.y; a[2] = (bf16_t)a0.z; a[3] = (bf16_t)a0.w;
                a[4] = (bf16_t)a1.x; a[5] = (bf16_t)a1.y; a[6] = (bf16_t)a1.z; a[7] = (bf16_t)a1.w;
                acc[mt][0] = MFMA16(a, bfr[0], acc[mt][0]);
                acc[mt][1] = MFMA16(a, bfr[1], acc[mt][1]);
            }
        }
#pragma unroll
        for (int mt = 0; mt < 4; ++mt) {
#pragma unroll
            for (int j = 0; j < 4; ++j) {
                const int k = mt * 16 + q * 4 + j;
                if (k < 49) {
                    const float bias = b2[g * 49 + k];
                    wgs[k * WGP + wv * 32 + l15]      = (bf16_t)(acc[mt][0][j] + bias);
                    wgs[k * WGP + wv * 32 + 16 + l15] = (bf16_t)(acc[mt][1][j] + bias);
                }
            }
        }
    }
    __syncthreads();

    // ---- phase2 agg: thread = (wq, r, cp) -> 2 ch x 4 w, direct-global feat ----
    const int wq = t & 15, r = (t >> 4) & 1, cp = t >> 5;   // cp in [0,8)
    const int w0 = wq * 4;
    const int ch0 = cp * 2;
    const bool q0v = (w0 > 0);      // quad at w0-4 valid
    const bool q2v = (w0 < 60);     // quad at w0+4 valid

    float acc[2][4] = {};
    const float* fbase = feat + ((size_t)(b * 256 + g * 16 + ch0) * 64) * 64;

#pragma unroll
    for (int di = 0; di < 7; ++di) {
        const int hh = h0 + r + di - 3;
        const bool rv = (hh >= 0) && (hh < 64);

        bf16x4 warr[7];
        const bf16_t* wrow = &wgs[(di * 7) * WGP + r * 64 + w0];
#pragma unroll
        for (int dj = 0; dj < 7; ++dj) warr[dj] = *(const bf16x4*)(wrow + dj * WGP);

#pragma unroll
        for (int c = 0; c < 2; ++c) {
            const float* fb = fbase + (size_t)c * 4096 + hh * 64;
            floatx4 f0 = {0.f, 0.f, 0.f, 0.f};
            floatx4 f1 = {0.f, 0.f, 0.f, 0.f};
            floatx4 f2 = {0.f, 0.f, 0.f, 0.f};
            if (rv && q0v) f0 = *(const floatx4*)(fb + w0 - 4);
            if (rv)        f1 = *(const floatx4*)(fb + w0);
            if (rv && q2v) f2 = *(const floatx4*)(fb + w0 + 4);
            float fw[12];
#pragma unroll
            for (int j = 0; j < 4; ++j) {
                fw[j] = f0[j]; fw[4 + j] = f1[j]; fw[8 + j] = f2[j];
            }
#pragma unroll
            for (int dj = 0; dj < 7; ++dj) {
                const bf16x4 wb = warr[dj];
#pragma unroll
                for (int x = 0; x < 4; ++x)
                    acc[c][x] = fmaf((float)wb[x], fw[x + dj + 1], acc[c][x]);
            }
        }
    }

    // residual: reload center quad (row h0+r always valid; L1/L2-hit) + store
#pragma unroll
    for (int c = 0; c < 2; ++c) {
        const floatx4 res = *(const floatx4*)(fbase + (size_t)c * 4096 + (h0 + r) * 64 + w0);
        const size_t ob = ((size_t)(b * 256 + g * 16 + ch0 + c) * 64 + h0 + r) * 64 + w0;
        float4 o;
        o.x = acc[c][0] + res[0]; o.y = acc[c][1] + res[1];
        o.z = acc[c][2] + res[2]; o.w = acc[c][3] + res[3];
        *(float4*)(out + ob) = o;
    }
}

extern "C" void kernel_launch(void* const* d_in, const int* in_sizes, int n_in,
                              void* d_out, int out_size, void* d_ws, size_t ws_size,
                              hipStream_t stream) {
    const float* feature = (const float*)d_in[0];
    const float* guide   = (const float*)d_in[1];
    const float* w1      = (const float*)d_in[2];
    const float* gamma   = (const float*)d_in[3];
    const float* beta    = (const float*)d_in[4];
    const float* mean    = (const float*)d_in[5];
    const float* var     = (const float*)d_in[6];
    const float* w2      = (const float*)d_in[7];
    const float* b2      = (const float*)d_in[8];
    float* out = (float*)d_out;

    bf16_t* xT = (bf16_t*)((char*)d_ws + XT_OFF);

    conv1_k<<<256, 512, 0, stream>>>(guide, w1, gamma, beta, mean, var, xT);
    fused_k<<<2048, 256, 0, stream>>>(xT, w2, b2, feature, out);
}

// Round 6
// 129.000 us; speedup vs baseline: 4.1403x; 1.1075x over previous
//
#include <hip/hip_runtime.h>

// B=4, C=256, CR=64, H=W=64, K=7, KK=49, GROUPS=16, GC=16
#define BN_EPS 1e-5f

typedef __bf16 bf16_t;
typedef __bf16 bf16x8 __attribute__((ext_vector_type(8)));
typedef __bf16 bf16x4 __attribute__((ext_vector_type(4)));
typedef __bf16 bf16x2 __attribute__((ext_vector_type(2)));
typedef float  floatx4 __attribute__((ext_vector_type(4)));

#define MFMA16(a, b, c) __builtin_amdgcn_mfma_f32_16x16x32_bf16((a), (b), (c), 0, 0, 0)

// ws layout: only xT (16384 px x 64 ch bf16 = 2 MB)
#define XT_OFF 0

// ---------------------------------------------------------------------------
// K1 conv1: one block per (b,h), 512 threads (2 waves/SIMD). w1 A-frags direct
// from global (L2-hot) with BN fold in regs; guide transpose staged in LDS.
// MFMA x[64o][64p]; +bias, ReLU; store xT[bp][o] (c-contiguous).
// ---------------------------------------------------------------------------
#define GTP 264

__global__ __launch_bounds__(512) void conv1_k(
    const float* __restrict__ guide, const float* __restrict__ w1,
    const float* __restrict__ gamma, const float* __restrict__ beta,
    const float* __restrict__ mean,  const float* __restrict__ var,
    bf16_t* __restrict__ xT)
{
    __shared__ __attribute__((aligned(16))) bf16_t gTs[64 * GTP];  // 33.8 KB
    const int b = blockIdx.x >> 6, h = blockIdx.x & 63;
    const int t = threadIdx.x;

    // stage guide row transposed: coalesced dword reads (lanes = p)
    const float* gsrc = guide + (size_t)b * 256 * 4096 + h * 64;
#pragma unroll
    for (int i = 0; i < 16; ++i) {
        const int idx = i * 512 + t;       // 8192 units = 128 c2 x 64 p
        const int c2 = idx >> 6, p = idx & 63;
        const float g0 = gsrc[(size_t)(2 * c2) * 4096 + p];
        const float g1 = gsrc[(size_t)(2 * c2 + 1) * 4096 + p];
        bf16x2 pk; pk[0] = (bf16_t)g0; pk[1] = (bf16_t)g1;
        *(bf16x2*)&gTs[p * GTP + 2 * c2] = pk;
    }
    __syncthreads();

    const int wv = t >> 6, ln = t & 63, l15 = ln & 15, q = ln >> 4;
    const int ot = wv & 3;          // o-tile: channels ot*16 .. +16
    const int ph = wv >> 2;         // p-half: pixels ph*32 .. +32
    const int o = ot * 16 + l15;    // A-row this lane reads
    const float iv = gamma[o] * rsqrtf(var[o] + BN_EPS);

    floatx4 acc[2] = {};
#pragma unroll
    for (int ks = 0; ks < 8; ++ks) {
        const float* wp = w1 + o * 256 + ks * 32 + q * 8;
        const float4 a0 = *(const float4*)(wp);
        const float4 a1 = *(const float4*)(wp + 4);
        bf16x8 a;
        a[0] = (bf16_t)(a0.x * iv); a[1] = (bf16_t)(a0.y * iv);
        a[2] = (bf16_t)(a0.z * iv); a[3] = (bf16_t)(a0.w * iv);
        a[4] = (bf16_t)(a1.x * iv); a[5] = (bf16_t)(a1.y * iv);
        a[6] = (bf16_t)(a1.z * iv); a[7] = (bf16_t)(a1.w * iv);
#pragma unroll
        for (int nt = 0; nt < 2; ++nt) {
            const bf16x8 bb = *(const bf16x8*)&gTs[(ph * 32 + nt * 16 + l15) * GTP + ks * 32 + q * 8];
            acc[nt] = MFMA16(a, bb, acc[nt]);
        }
    }
    float bi[4];
#pragma unroll
    for (int j = 0; j < 4; ++j) {
        const int o2 = ot * 16 + q * 4 + j;
        const float iv2 = gamma[o2] * rsqrtf(var[o2] + BN_EPS);
        bi[j] = beta[o2] - mean[o2] * iv2;
    }
#pragma unroll
    for (int nt = 0; nt < 2; ++nt) {
        const int p = ph * 32 + nt * 16 + l15;
        bf16x4 v;
#pragma unroll
        for (int j = 0; j < 4; ++j) v[j] = (bf16_t)fmaxf(acc[nt][j] + bi[j], 0.f);
        *(bf16x4*)(xT + ((size_t)(b * 64 + h) * 64 + p) * 64 + ot * 16 + q * 4) = v;
    }
}

// ---------------------------------------------------------------------------
// K2 conv2+agg fused: block = (g, b, h-pair), grid 2048, 256 thr.
// R1 skeleton (proven best: fs-staged LDS, 3 blocks/CU) + ILP fixes:
//  - async-stage split (T14): issue all 9 predicated feat float4 loads into
//    REGS first; MFMA phase runs while they fly; ds_write fs after; 1 barrier.
//  - depth-2 software-pipelined agg with explicitly-named stage regs (no
//    runtime indexing -> no scratch): preload di+1's {7 wgs b64, 6 fs b128}
//    while FMA-ing di. Turns 7 serial LDS latencies into ~1.
//  - FSC 576->584: 2-ch bank alias (==0 mod 32) -> 16-bank offset.
// LDS = fs 37.4 KB + wgs 13.3 KB = 50.7 KB -> 3 blocks/CU. No min-waves bound
// (R4: (256,6) caused 1.5 GB scratch spill). XCD = g%8 -> feat slice L2-hot.
// ---------------------------------------------------------------------------
#define FSR 72     // fs row pitch (floats): [4 pad][64 w][4 pad]
#define FSC 584    // fs channel pitch (8*72 + 8 pad)
#define WGP 136    // wgs row pitch (bf16)

__global__ __launch_bounds__(256) void fused_k(
    const bf16_t* __restrict__ xT, const float* __restrict__ w2,
    const float* __restrict__ b2,  const float* __restrict__ feat,
    float* __restrict__ out)
{
    __shared__ __attribute__((aligned(16))) float  fs[16 * FSC];   // 37.4 KB
    __shared__ __attribute__((aligned(16))) bf16_t wgs[49 * WGP];  // 13.3 KB

    const int g = blockIdx.x & 15;
    const int rest = blockIdx.x >> 4;      // 0..127
    const int b = rest >> 5, hp = rest & 31;
    const int h0 = hp * 2;
    const int t = threadIdx.x;
    const int wv = t >> 6, ln = t & 63, l15 = ln & 15, q = ln >> 4;

    // ---- phase0: ISSUE fs loads into regs (complete during MFMA phase) ----
    float4 fsv[9];
    int    fsa[9];
#pragma unroll
    for (int i = 0; i < 9; ++i) {
        const int u = i * 256 + t;         // 2304 quads
        const int c = u / 144, rem = u - c * 144;
        const int rr = rem / 18, qq = rem - rr * 18;
        const int hh = h0 - 3 + rr;
        float4 v = {0.f, 0.f, 0.f, 0.f};
        if (qq >= 1 && qq <= 16 && hh >= 0 && hh < 64)
            v = *(const float4*)(feat + ((size_t)(b * 256 + g * 16 + c) * 64 + hh) * 64 + (qq - 1) * 4);
        fsv[i] = v;
        fsa[i] = c * FSC + rr * FSR + qq * 4;
    }

    // ---- phase1 MFMA: wg[49 x 128] = w2[g] . xT ; A cvt'd from fp32 in regs ----
    {
        floatx4 acc[4][2] = {};
        const bf16_t* brow = xT + ((size_t)(b * 64 + h0) * 64 + wv * 32) * 64;
#pragma unroll
        for (int ks = 0; ks < 2; ++ks) {
            bf16x8 bfr[2];
            bfr[0] = *(const bf16x8*)(brow + l15 * 64 + ks * 32 + q * 8);
            bfr[1] = *(const bf16x8*)(brow + (16 + l15) * 64 + ks * 32 + q * 8);
#pragma unroll
            for (int mt = 0; mt < 4; ++mt) {
                int row = mt * 16 + l15; if (row > 48) row = 48;  // pad rows never stored
                const float* wp = w2 + (size_t)(g * 49 + row) * 64 + ks * 32 + q * 8;
                const float4 a0 = *(const float4*)(wp);
                const float4 a1 = *(const float4*)(wp + 4);
                bf16x8 a;
                a[0] = (bf16_t)a0.x; a[1] = (bf16_t)a0.y; a[2] = (bf16_t)a0.z; a[3] = (bf16_t)a0.w;
                a[4] = (bf16_t)a1.x; a[5] = (bf16_t)a1.y; a[6] = (bf16_t)a1.z; a[7] = (bf16_t)a1.w;
                acc[mt][0] = MFMA16(a, bfr[0], acc[mt][0]);
                acc[mt][1] = MFMA16(a, bfr[1], acc[mt][1]);
            }
        }
#pragma unroll
        for (int mt = 0; mt < 4; ++mt) {
#pragma unroll
            for (int j = 0; j < 4; ++j) {
                const int k = mt * 16 + q * 4 + j;
                if (k < 49) {
                    const float bias = b2[g * 49 + k];
                    wgs[k * WGP + wv * 32 + l15]      = (bf16_t)(acc[mt][0][j] + bias);
                    wgs[k * WGP + wv * 32 + 16 + l15] = (bf16_t)(acc[mt][1][j] + bias);
                }
            }
        }
    }

    // ---- write staged fs regs to LDS (loads have completed under phase1) ----
#pragma unroll
    for (int i = 0; i < 9; ++i)
        *(float4*)&fs[fsa[i]] = fsv[i];
    __syncthreads();

    // ---- agg: thread = (wq, r, cp) -> 2 ch x 4 w; depth-2 pipelined over di ----
    const int wq = t & 15, r = (t >> 4) & 1, cp = t >> 5;   // cp in [0,8)
    const int w0 = wq * 4;
    const int ch0 = cp * 2;

#define LOAD_STAGE(di, WA, FA, FB) do {                                        \
        const bf16_t* wrow_ = &wgs[((di) * 7) * WGP + r * 64 + w0];            \
        _Pragma("unroll")                                                      \
        for (int dj = 0; dj < 7; ++dj) WA[dj] = *(const bf16x4*)(wrow_ + dj * WGP); \
        const float* p0_ = &fs[ch0 * FSC + ((di) + r) * FSR + w0];             \
        const float* p1_ = p0_ + FSC;                                          \
        _Pragma("unroll")                                                      \
        for (int qj = 0; qj < 3; ++qj) {                                       \
            FA[qj] = *(const floatx4*)(p0_ + qj * 4);                          \
            FB[qj] = *(const floatx4*)(p1_ + qj * 4);                          \
        }                                                                      \
    } while (0)

#define FMA_STAGE(WA, FA, FB) do {                                             \
        _Pragma("unroll")                                                      \
        for (int dj = 0; dj < 7; ++dj) {                                       \
            const bf16x4 wb_ = WA[dj];                                         \
            _Pragma("unroll")                                                  \
            for (int x = 0; x < 4; ++x) {                                      \
                const int e = x + dj + 1;                                      \
                const float wf_ = (float)wb_[x];                               \
                acc[0][x] = fmaf(wf_, FA[e >> 2][e & 3], acc[0][x]);           \
                acc[1][x] = fmaf(wf_, FB[e >> 2][e & 3], acc[1][x]);           \
            }                                                                  \
        }                                                                      \
    } while (0)

    float acc[2][4] = {};
    bf16x4 waA[7], waB[7];
    floatx4 faA[3], fbA[3], faB[3], fbB[3];

    LOAD_STAGE(0, waA, faA, fbA);
    LOAD_STAGE(1, waB, faB, fbB);
    FMA_STAGE(waA, faA, fbA);
    LOAD_STAGE(2, waA, faA, fbA);
    FMA_STAGE(waB, faB, fbB);
    LOAD_STAGE(3, waB, faB, fbB);
    FMA_STAGE(waA, faA, fbA);
    LOAD_STAGE(4, waA, faA, fbA);
    FMA_STAGE(waB, faB, fbB);
    LOAD_STAGE(5, waB, faB, fbB);
    FMA_STAGE(waA, faA, fbA);
    LOAD_STAGE(6, waA, faA, fbA);
    FMA_STAGE(waB, faB, fbB);
    FMA_STAGE(waA, faA, fbA);

#undef LOAD_STAGE
#undef FMA_STAGE

    // residual from staged fp32 tile (row r+3 == h0+r), + store
#pragma unroll
    for (int c = 0; c < 2; ++c) {
        const floatx4 res = *(const floatx4*)&fs[(ch0 + c) * FSC + (r + 3) * FSR + 4 + w0];
        const size_t ob = ((size_t)(b * 256 + g * 16 + ch0 + c) * 64 + h0 + r) * 64 + w0;
        float4 o;
        o.x = acc[c][0] + res[0]; o.y = acc[c][1] + res[1];
        o.z = acc[c][2] + res[2]; o.w = acc[c][3] + res[3];
        *(float4*)(out + ob) = o;
    }
}

extern "C" void kernel_launch(void* const* d_in, const int* in_sizes, int n_in,
                              void* d_out, int out_size, void* d_ws, size_t ws_size,
                              hipStream_t stream) {
    const float* feature = (const float*)d_in[0];
    const float* guide   = (const float*)d_in[1];
    const float* w1      = (const float*)d_in[2];
    const float* gamma   = (const float*)d_in[3];
    const float* beta    = (const float*)d_in[4];
    const float* mean    = (const float*)d_in[5];
    const float* var     = (const float*)d_in[6];
    const float* w2      = (const float*)d_in[7];
    const float* b2      = (const float*)d_in[8];
    float* out = (float*)d_out;

    bf16_t* xT = (bf16_t*)((char*)d_ws + XT_OFF);

    conv1_k<<<256, 512, 0, stream>>>(guide, w1, gamma, beta, mean, var, xT);
    fused_k<<<2048, 256, 0, stream>>>(xT, w2, b2, feature, out);
}